// Round 16
// baseline (173.719 us; speedup 1.0000x reference)
//
#include <hip/hip_runtime.h>

typedef float f4v __attribute__((ext_vector_type(4)));

namespace {
constexpr int Bn = 4, Cn = 32, Dn = 48, Hn = 64, Wn = 128;
constexpr int HQ = 32, WQ = 64;
constexpr int NPB = Dn * HQ * WQ;   // 98304 pooled positions / batch
constexpr int DHW = Dn * Hn * Wn;   // 393216
constexpr int PERB = Cn * DHW;      // 12582912 elements / batch
constexpr int NS = 128, En = 12;
constexpr float EPS = 1e-5f;
constexpr float SQK = 0.2886751345948129f;  // 1/sqrt(12)
constexpr int NB1 = 384;                    // grid.x of k1 (256 cells/block)
constexpr int NBA = 128;                    // grid.x of attn (768 positions/block)

// workspace float offsets
constexpr size_t OFF_ZB  = 0;                      // bf16[4*32*98304] -> 6291456 floats
constexpr size_t OFF_QP  = 6291456;                // u32[4*12*98304] -> 4718592 floats (lo=q, hi=pw)
constexpr size_t OFF_P1  = OFF_QP + 4718592;       // float2[4*384] -> 3072 floats
constexpr size_t OFF_P2  = OFF_P1 + 3072;          // float4[4*128] -> 2048 floats
constexpr size_t OFF_PKV = OFF_P2 + 2048;          // 16*128*24 = 49152
}  // namespace

__device__ inline unsigned short bf16b(float x) {
    unsigned u = __float_as_uint(x);
    return (unsigned short)((u + 0x7fffu + ((u >> 16) & 1u)) >> 16);
}
__device__ inline float b2f(unsigned short h) { return __uint_as_float(((unsigned)h) << 16); }
__device__ inline float bf16_rne(float x) {
    unsigned u = __float_as_uint(x);
    u = (u + 0x7fffu + ((u >> 16) & 1u)) & 0xffff0000u;
    return __uint_as_float(u);
}

// block = 256 threads; reentrant-safe.
__device__ inline float2 block_red2(float s, float ss) {
#pragma unroll
    for (int off = 32; off; off >>= 1) {
        s += __shfl_down(s, off, 64);
        ss += __shfl_down(ss, off, 64);
    }
    __shared__ float red[8];
    int lane = threadIdx.x & 63, w = threadIdx.x >> 6;
    __syncthreads();
    if (!lane) { red[w] = s; red[4 + w] = ss; }
    __syncthreads();
    return make_float2(red[0] + red[1] + red[2] + red[3],
                       red[4] + red[5] + red[6] + red[7]);
}

// ---------- K1: pool (1 cell/thread) + packed q/pw (NT) + exact stats + K/V partials ----------
__global__ __launch_bounds__(256) void k1_pool(const float* __restrict__ cost,
                                               const float* __restrict__ feat,
                                               const float* __restrict__ w_q,
                                               const float* __restrict__ w_k,
                                               const float* __restrict__ w_v,
                                               const float* __restrict__ w_out,
                                               const float* __restrict__ gniw,
                                               unsigned* __restrict__ qp,
                                               float2* __restrict__ part1,
                                               float* __restrict__ pkv) {
    __shared__ float wqg[En * Cn], WOs[Cn * En];
    const int b = blockIdx.y, tid = threadIdx.x;
    for (int i = tid; i < En * Cn; i += 256) {
        wqg[i] = w_q[i] * gniw[i & 31];
        WOs[i] = w_out[i];
    }
    __syncthreads();
    const int n = blockIdx.x * 256 + tid;
    const int d = n >> 11, r = n & 2047, hq = r >> 6, wq = r & 63;
    const float* base = cost + (size_t)b * PERB + (size_t)d * 8192 + (hq * 2) * Wn + wq * 2;
    float s = 0.f, ss = 0.f;
    float q[En], pw[En];
#pragma unroll
    for (int e = 0; e < En; ++e) { q[e] = 0.f; pw[e] = 0.f; }
#pragma unroll 4
    for (int c = 0; c < Cn; ++c) {
        const float* src = base + (size_t)c * DHW;
        float2 t0 = *reinterpret_cast<const float2*>(src);
        float2 t1 = *reinterpret_cast<const float2*>(src + Wn);
        float ps = t0.x + t0.y + t1.x + t1.y;
        s += ps;
        ss += t0.x * t0.x + t0.y * t0.y + t1.x * t1.x + t1.y * t1.y;
        float pv = 0.25f * ps;
#pragma unroll
        for (int e = 0; e < En; ++e) {
            q[e] += wqg[e * Cn + c] * pv;
            pw[e] += WOs[c * En + e] * pv;
        }
    }
#pragma unroll
    for (int e = 0; e < En; ++e) {
        unsigned pk = (unsigned)bf16b(q[e]) | ((unsigned)bf16b(pw[e]) << 16);
        __builtin_nontemporal_store(pk, qp + (size_t)(b * En + e) * NPB + n);
    }
    float2 rp = block_red2(s, ss);
    if (!tid) part1[b * NB1 + blockIdx.x] = rp;

    // K/V partials: 16 blocks (b==0, x<16). g = x: kb = g>>2 (batch), cg = g&3 (64-ch group)
    if (b == 0 && blockIdx.x < 16 && tid < NS) {
        const int g = blockIdx.x, kb = g >> 2, cg = g & 3, sI = tid;
        float kk[En], vv[En];
#pragma unroll
        for (int e = 0; e < En; ++e) { kk[e] = 0.f; vv[e] = 0.f; }
        for (int ch = 0; ch < 4; ++ch) {
            const int c0 = cg * 64 + ch * 16;
            float f[16];
#pragma unroll
            for (int jj = 0; jj < 16; ++jj) f[jj] = feat[(size_t)(kb * 256 + c0 + jj) * NS + sI];
#pragma unroll
            for (int jj = 0; jj < 16; ++jj) {
                const int c = c0 + jj;
#pragma unroll
                for (int e = 0; e < En; ++e) {
                    kk[e] += w_k[e * 256 + c] * f[jj];
                    vv[e] += w_v[e * 256 + c] * f[jj];
                }
            }
        }
#pragma unroll
        for (int e = 0; e < En; ++e) {
            pkv[((size_t)(g * NS + sI)) * 24 + e] = kk[e];
            pkv[((size_t)(g * NS + sI)) * 24 + 12 + e] = vv[e];
        }
    }
}

// ---------- K2: attention (3 pos/thread) + zb(NT) + Gram-form analytic stats ----------
__global__ __launch_bounds__(256) void k_attn(const unsigned* __restrict__ qp,
                                              const float* __restrict__ pkv,
                                              const float* __restrict__ w_q,
                                              const float* __restrict__ gniw,
                                              const float* __restrict__ gnib,
                                              const float2* __restrict__ part1,
                                              const float* __restrict__ w_out,
                                              unsigned short* __restrict__ zb,
                                              float4* __restrict__ part2) {
    __shared__ float Ks[NS * En], Vs[NS * En], WOs[Cn * En], QBs[En];
    __shared__ float G[En * En], woSum[En];
    __shared__ float kred[2], kscs_sh;
    const int x = blockIdx.x, b = blockIdx.y, tid = threadIdx.x;
    const int u = tid >> 6, lane = tid & 63;

    // exact GN-in stats from part1
    float sP = 0.f, ssP = 0.f;
    for (int i = tid; i < NB1; i += 256) {
        float2 v = part1[b * NB1 + i];
        sP += v.x; ssP += v.y;
    }
    float2 tP = block_red2(sP, ssP);
    const float mGN = tP.x / (float)PERB;
    const float rsGN = rsqrtf(tP.y / (float)PERB - mGN * mGN + EPS);
    const float qsc = rsGN * SQK;

    // combine K/V partials, weights, q-bias
    for (int i = tid; i < NS * En; i += 256) {
        int s = i / En, e = i - s * En;
        size_t base = ((size_t)((b * 4) * NS + s)) * 24 + e;
        Ks[i] = pkv[base] + pkv[base + 3072] + pkv[base + 6144] + pkv[base + 9216];
        Vs[i] = pkv[base + 12] + pkv[base + 3084] + pkv[base + 6156] + pkv[base + 9228];
    }
    for (int i = tid; i < Cn * En; i += 256) WOs[i] = w_out[i];
    if (tid < En) {
        float acc = 0.f;
        for (int c = 0; c < Cn; ++c)
            acc += w_q[tid * Cn + c] * (gnib[c] - mGN * rsGN * gniw[c]);
        QBs[tid] = SQK * acc;
    }
    __syncthreads();
    // Gram matrix, column sums, kscs
    if (tid < 144) {
        int e1 = tid / 12, e2 = tid - e1 * 12;
        float a = 0.f;
        for (int c = 0; c < Cn; ++c) a += WOs[c * En + e1] * WOs[c * En + e2];
        G[tid] = a;
    }
    if (tid >= 144 && tid < 156) {
        int e = tid - 144;
        float a = 0.f;
        for (int c = 0; c < Cn; ++c) a += WOs[c * En + e];
        woSum[e] = a;
    }
    if (tid < NS) {
        float n2 = 0.f;
#pragma unroll
        for (int e = 0; e < En; ++e) { float k = Ks[tid * En + e]; n2 += k * k; }
#pragma unroll
        for (int off = 32; off; off >>= 1) n2 = fmaxf(n2, __shfl_down(n2, off, 64));
        if (!(tid & 63)) kred[tid >> 6] = n2;
    }
    __syncthreads();
    if (!tid) kscs_sh = sqrtf(fmaxf(kred[0], kred[1]));
    __syncthreads();
    const float kscs = kscs_sh;

    // positions: n_p = x*768 + (u*3+p)*64 + lane  (3 consecutive h-rows; w == lane)
    int npos[3];
#pragma unroll
    for (int p = 0; p < 3; ++p) npos[p] = x * 768 + (u * 3 + p) * 64 + lane;

    f4v q[3][3];
    float ub[3];
#pragma unroll
    for (int p = 0; p < 3; ++p) {
        const int n = npos[p];
        float qn2 = 0.f;
#pragma unroll
        for (int v = 0; v < 3; ++v) {
            f4v t;
#pragma unroll
            for (int uu = 0; uu < 4; ++uu) {
                int e = v * 4 + uu;
                unsigned pk = __builtin_nontemporal_load(qp + (size_t)(b * En + e) * NPB + n);
                float qe = qsc * b2f((unsigned short)(pk & 0xffffu)) + QBs[e];
                t[uu] = qe;
                qn2 += qe * qe;
            }
            q[p][v] = t;
        }
        ub[p] = sqrtf(qn2) * kscs;  // Cauchy-Schwarz >= max logit
    }

    f4v o0[3], o1[3], o2[3];
    float l[3];
#pragma unroll
    for (int p = 0; p < 3; ++p) {
        o0[p] = (f4v)(0.f); o1[p] = (f4v)(0.f); o2[p] = (f4v)(0.f);
        l[p] = 0.f;
    }
    const f4v* K4 = (const f4v*)Ks;
    const f4v* V4 = (const f4v*)Vs;
    for (int s = 0; s < NS; ++s) {
        f4v k0 = K4[s * 3], k1 = K4[s * 3 + 1], k2 = K4[s * 3 + 2];
        f4v v0 = V4[s * 3], v1 = V4[s * 3 + 1], v2 = V4[s * 3 + 2];
#pragma unroll
        for (int p = 0; p < 3; ++p) {
            f4v d4 = q[p][0] * k0 + q[p][1] * k1 + q[p][2] * k2;
            float dot = (d4.x + d4.y) + (d4.z + d4.w);
            float pe = __expf(dot - ub[p]);
            l[p] += pe;
            o0[p] += pe * v0; o1[p] += pe * v1; o2[p] += pe * v2;
        }
    }

    // h = o / l
    float hv[3][En];
#pragma unroll
    for (int p = 0; p < 3; ++p) {
        float iv = 1.0f / l[p];
#pragma unroll
        for (int uu = 0; uu < 4; ++uu) {
            hv[p][uu] = o0[p][uu] * iv;
            hv[p][4 + uu] = o1[p][uu] * iv;
            hv[p][8 + uu] = o2[p][uu] * iv;
        }
    }

    // per-channel Z -> zb (bf16, NT)
    for (int c = 0; c < Cn; ++c) {
        float z[3];
#pragma unroll
        for (int p = 0; p < 3; ++p) {
            float a = 0.f;
#pragma unroll
            for (int e = 0; e < En; ++e) a += WOs[c * En + e] * hv[p][e];
            z[p] = a;
        }
#pragma unroll
        for (int p = 0; p < 3; ++p)
            __builtin_nontemporal_store(bf16b(z[p]),
                                        zb + (size_t)(b * Cn + c) * NPB + npos[p]);
    }

    // sz, spz  (pw = hi half of qp)
    float sz = 0.f, spz = 0.f;
#pragma unroll
    for (int p = 0; p < 3; ++p) {
#pragma unroll
        for (int e = 0; e < En; ++e) {
            sz += woSum[e] * hv[p][e];
            unsigned pk = __builtin_nontemporal_load(qp + (size_t)(b * En + e) * NPB + npos[p]);
            spz += b2f((unsigned short)(pk >> 16)) * hv[p][e];
        }
    }

    // shuffled neighbors (w+1): zero at lane 63 (slice edge)
    const bool okw = (lane < 63);
    float hs[3][En];
#pragma unroll
    for (int p = 0; p < 3; ++p)
#pragma unroll
        for (int e = 0; e < En; ++e) {
            float t = __shfl_down(hv[p][e], 1, 64);
            hs[p][e] = okw ? t : 0.f;
        }

    // geometry weights
    float hD[3];
    bool hOk[3];
#pragma unroll
    for (int p = 0; p < 3; ++p) {
        int h = (x * 12 + u * 3 + p) & 31;
        hD[p] = (h == 0 || h == 31) ? 1.625f : 1.25f;
        hOk[p] = (h < 31) && (p < 2);
    }
    const float Dw = (lane == 0 || lane == 63) ? 1.625f : 1.25f;

    // t2 via Gram
    float t2 = 0.f;
#pragma unroll
    for (int p = 0; p < 3; ++p) {
        float Gh[En];
#pragma unroll
        for (int e = 0; e < En; ++e) {
            float a = 0.f;
#pragma unroll
            for (int f = 0; f < En; ++f) a += G[e * En + f] * hv[p][f];
            Gh[e] = a;
        }
        float gpp = 0.f, gw = 0.f;
#pragma unroll
        for (int e = 0; e < En; ++e) {
            gpp += Gh[e] * hv[p][e];
            gw += Gh[e] * hs[p][e];
        }
        t2 += hD[p] * Dw * gpp + 0.75f * hD[p] * gw;
        if (p < 2 && hOk[p]) {
            float ghp = 0.f, gd1 = 0.f;
#pragma unroll
            for (int e = 0; e < En; ++e) {
                ghp += Gh[e] * hv[p + 1][e];
                gd1 += Gh[e] * hs[p + 1][e];
            }
            t2 += 0.75f * Dw * ghp + 0.28125f * gd1;
        }
        if (p > 0 && hOk[p - 1]) {
            float gd2 = 0.f;
#pragma unroll
            for (int e = 0; e < En; ++e) gd2 += Gh[e] * hs[p - 1][e];
            t2 += 0.28125f * gd2;
        }
    }
    float2 rA = block_red2(sz, spz);
    float2 rB = block_red2(t2, 0.f);
    if (!tid) part2[b * NBA + x] = make_float4(rA.x, rA.y, rB.x, 0.f);
}

// ---------- K3: final GroupNorm (analytic stats2 in prologue), hoisted upsample ----------
__global__ __launch_bounds__(256) void k_final(const float* __restrict__ cost,
                                               const unsigned short* __restrict__ zb,
                                               const float* __restrict__ gamma_p,
                                               const float2* __restrict__ part1,
                                               const float4* __restrict__ part2,
                                               const float* __restrict__ gow,
                                               const float* __restrict__ gob,
                                               float* __restrict__ out) {
    const int blk = blockIdx.x;
    const int b = blk / (Cn * Dn);
    const int c = (blk / Dn) % Cn;
    const int tid = threadIdx.x;
    const float g = gamma_p[0];

    // analytic stats2: Sy = Sc + 4g*SZ ; Syy = Scc + 8g*SPZ + g^2*T2
    float sc_ = 0.f, scc = 0.f;
    for (int i = tid; i < NB1; i += 256) {
        float2 v = part1[b * NB1 + i];
        sc_ += v.x; scc += v.y;
    }
    float2 tA = block_red2(sc_, scc);
    float sz = 0.f, spz = 0.f, t2 = 0.f;
    if (tid < NBA) {
        float4 v = part2[b * NBA + tid];
        sz = v.x; spz = v.y; t2 = v.z;
    }
    float2 tB = block_red2(sz, spz);
    float2 tC = block_red2(t2, 0.f);
    const float Sy = tA.x + 4.f * g * tB.x;
    const float Syy = tA.y + 8.f * g * tB.y + g * g * tC.x;
    const float m = Sy / (float)PERB;
    const float var = Syy / (float)PERB - m * m;
    const float rs = rsqrtf(var + EPS);

    // stage z-slice as FLOATS (8 KB), NT loads
    __shared__ float zs[HQ * WQ];
    {
        const unsigned int* zsrc = (const unsigned int*)(zb + (size_t)blk * 2048);
        for (int i = tid; i < 1024; i += 256) {
            unsigned v = __builtin_nontemporal_load(zsrc + i);
            zs[2 * i] = b2f((unsigned short)(v & 0xffffu));
            zs[2 * i + 1] = b2f((unsigned short)(v >> 16));
        }
    }
    __syncthreads();
    const float sc = rs * gow[c], bi = gob[c];
    const f4v* cq = (const f4v*)(cost + (size_t)blk * 8192);
    f4v* oq = (f4v*)(out + (size_t)blk * 8192);

    // thread-invariant upsample geometry
    const int hbase = tid >> 5;           // 0..7
    const int w4 = (tid & 31) << 2;       // 0..124
    const float wh0 = (hbase & 1) ? 0.75f : 0.25f;
    const float wh1 = 1.0f - wh0;
    const int ia = (w4 >> 1) - 1 < 0 ? 0 : (w4 >> 1) - 1;
    const int ib = w4 >> 1;
    const int ic = (w4 >> 1) + 1;
    const int id = (w4 >> 1) + 2 > WQ - 1 ? WQ - 1 : (w4 >> 1) + 2;

#pragma unroll
    for (int k = 0; k < 8; ++k) {
        const int h = hbase + 8 * k;
        int h0 = (h - 1) >> 1;
        h0 = h0 < 0 ? 0 : h0;
        int h1 = h0 + 1;
        h1 = h1 > HQ - 1 ? HQ - 1 : h1;
        const float* r0 = zs + h0 * WQ;
        const float* r1 = zs + h1 * WQ;
        const float a0 = r0[ia], b0 = r0[ib], c0 = r0[ic], d0 = r0[id];
        const float a1 = r1[ia], b1 = r1[ib], c1 = r1[ic], d1 = r1[id];
        const float t0j = 0.25f * a0 + 0.75f * b0, u0j = 0.25f * a1 + 0.75f * b1;
        const float t1j = 0.75f * b0 + 0.25f * c0, u1j = 0.75f * b1 + 0.25f * c1;
        const float t2j = 0.25f * b0 + 0.75f * c0, u2j = 0.25f * b1 + 0.75f * c1;
        const float t3j = 0.75f * c0 + 0.25f * d0, u3j = 0.75f * c1 + 0.25f * d1;
        const int qd = tid + 256 * k;
        f4v cv = cq[qd];
        f4v ov;
        ov.x = (cv.x + g * bf16_rne(wh0 * t0j + wh1 * u0j) - m) * sc + bi;
        ov.y = (cv.y + g * bf16_rne(wh0 * t1j + wh1 * u1j) - m) * sc + bi;
        ov.z = (cv.z + g * bf16_rne(wh0 * t2j + wh1 * u2j) - m) * sc + bi;
        ov.w = (cv.w + g * bf16_rne(wh0 * t3j + wh1 * u3j) - m) * sc + bi;
        __builtin_nontemporal_store(ov, oq + qd);
    }
}

extern "C" void kernel_launch(void* const* d_in, const int* in_sizes, int n_in,
                              void* d_out, int out_size, void* d_ws, size_t ws_size,
                              hipStream_t stream) {
    const float* cost  = (const float*)d_in[0];
    const float* feat  = (const float*)d_in[1];
    const float* w_q   = (const float*)d_in[2];
    const float* w_k   = (const float*)d_in[3];
    const float* w_v   = (const float*)d_in[4];
    const float* w_out = (const float*)d_in[5];
    const float* gniw  = (const float*)d_in[6];
    const float* gnib  = (const float*)d_in[7];
    const float* gow   = (const float*)d_in[8];
    const float* gob   = (const float*)d_in[9];
    const float* gamma = (const float*)d_in[10];

    float* ws = (float*)d_ws;
    float* outp = (float*)d_out;

    unsigned short* zb = (unsigned short*)(ws + OFF_ZB);
    unsigned* qp = (unsigned*)(ws + OFF_QP);
    float2* part1 = (float2*)(ws + OFF_P1);
    float4* part2 = (float4*)(ws + OFF_P2);
    float* pkv = ws + OFF_PKV;

    k1_pool<<<dim3(NB1, Bn), 256, 0, stream>>>(cost, feat, w_q, w_k, w_v, w_out, gniw,
                                               qp, part1, pkv);
    k_attn<<<dim3(NBA, Bn), 256, 0, stream>>>(qp, pkv, w_q, gniw, gnib, part1,
                                              w_out, zb, part2);
    k_final<<<Bn * Cn * Dn, 256, 0, stream>>>(cost, zb, gamma, part1, part2, gow, gob, outp);
}

// Round 17
// 172.915 us; speedup vs baseline: 1.0047x; 1.0047x over previous
//
#include <hip/hip_runtime.h>

typedef float f4v __attribute__((ext_vector_type(4)));

namespace {
constexpr int Bn = 4, Cn = 32, Dn = 48, Hn = 64, Wn = 128;
constexpr int HQ = 32, WQ = 64;
constexpr int NPB = Dn * HQ * WQ;   // 98304 pooled positions / batch
constexpr int DHW = Dn * Hn * Wn;   // 393216
constexpr int PERB = Cn * DHW;      // 12582912 elements / batch
constexpr int NS = 128, En = 12;
constexpr float EPS = 1e-5f;
constexpr float SQK = 0.2886751345948129f;  // 1/sqrt(12)
constexpr int NB1 = 384;                    // grid.x of k1 (256 cells/block)
constexpr int NBA = 128;                    // grid.x of attn (768 positions/block)

// workspace float offsets
constexpr size_t OFF_ZB  = 0;                      // bf16[4*32*98304] -> 6291456 floats
constexpr size_t OFF_QP  = 6291456;                // u32[4*12*98304] -> 4718592 floats (lo=q, hi=pw)
constexpr size_t OFF_P1  = OFF_QP + 4718592;       // float2[4*384] -> 3072 floats
constexpr size_t OFF_P2  = OFF_P1 + 3072;          // float4[4*128] -> 2048 floats
constexpr size_t OFF_ST2 = OFF_P2 + 2048;          // float2[4] -> 8 floats
constexpr size_t OFF_PKV = OFF_ST2 + 8;            // 16*128*24 = 49152
}  // namespace

__device__ inline unsigned short bf16b(float x) {
    unsigned u = __float_as_uint(x);
    return (unsigned short)((u + 0x7fffu + ((u >> 16) & 1u)) >> 16);
}
__device__ inline float b2f(unsigned short h) { return __uint_as_float(((unsigned)h) << 16); }
__device__ inline float bf16_rne(float x) {
    unsigned u = __float_as_uint(x);
    u = (u + 0x7fffu + ((u >> 16) & 1u)) & 0xffff0000u;
    return __uint_as_float(u);
}

// block = 256 threads; reentrant-safe.
__device__ inline float2 block_red2(float s, float ss) {
#pragma unroll
    for (int off = 32; off; off >>= 1) {
        s += __shfl_down(s, off, 64);
        ss += __shfl_down(ss, off, 64);
    }
    __shared__ float red[8];
    int lane = threadIdx.x & 63, w = threadIdx.x >> 6;
    __syncthreads();
    if (!lane) { red[w] = s; red[4 + w] = ss; }
    __syncthreads();
    return make_float2(red[0] + red[1] + red[2] + red[3],
                       red[4] + red[5] + red[6] + red[7]);
}

// ---------- K1: pool (1 cell/thread) + packed q/pw + exact stats + K/V partials ----------
__global__ __launch_bounds__(256) void k1_pool(const float* __restrict__ cost,
                                               const float* __restrict__ feat,
                                               const float* __restrict__ w_q,
                                               const float* __restrict__ w_k,
                                               const float* __restrict__ w_v,
                                               const float* __restrict__ w_out,
                                               const float* __restrict__ gniw,
                                               unsigned* __restrict__ qp,
                                               float2* __restrict__ part1,
                                               float* __restrict__ pkv) {
    __shared__ float wqg[En * Cn], WOs[Cn * En];
    const int b = blockIdx.y, tid = threadIdx.x;
    for (int i = tid; i < En * Cn; i += 256) {
        wqg[i] = w_q[i] * gniw[i & 31];
        WOs[i] = w_out[i];
    }
    __syncthreads();
    const int n = blockIdx.x * 256 + tid;
    const int d = n >> 11, r = n & 2047, hq = r >> 6, wq = r & 63;
    const float* base = cost + (size_t)b * PERB + (size_t)d * 8192 + (hq * 2) * Wn + wq * 2;
    float s = 0.f, ss = 0.f;
    float q[En], pw[En];
#pragma unroll
    for (int e = 0; e < En; ++e) { q[e] = 0.f; pw[e] = 0.f; }
#pragma unroll 4
    for (int c = 0; c < Cn; ++c) {
        const float* src = base + (size_t)c * DHW;
        float2 t0 = *reinterpret_cast<const float2*>(src);
        float2 t1 = *reinterpret_cast<const float2*>(src + Wn);
        float ps = t0.x + t0.y + t1.x + t1.y;
        s += ps;
        ss += t0.x * t0.x + t0.y * t0.y + t1.x * t1.x + t1.y * t1.y;
        float pv = 0.25f * ps;
#pragma unroll
        for (int e = 0; e < En; ++e) {
            q[e] += wqg[e * Cn + c] * pv;
            pw[e] += WOs[c * En + e] * pv;
        }
    }
#pragma unroll
    for (int e = 0; e < En; ++e) {
        unsigned pk = (unsigned)bf16b(q[e]) | ((unsigned)bf16b(pw[e]) << 16);
        qp[(size_t)(b * En + e) * NPB + n] = pk;   // regular store: stays L2/L3-hot for attn
    }
    float2 rp = block_red2(s, ss);
    if (!tid) part1[b * NB1 + blockIdx.x] = rp;

    // K/V partials: 16 blocks (b==0, x<16). g = x: kb = g>>2 (batch), cg = g&3 (64-ch group)
    if (b == 0 && blockIdx.x < 16 && tid < NS) {
        const int g = blockIdx.x, kb = g >> 2, cg = g & 3, sI = tid;
        float kk[En], vv[En];
#pragma unroll
        for (int e = 0; e < En; ++e) { kk[e] = 0.f; vv[e] = 0.f; }
        for (int ch = 0; ch < 4; ++ch) {
            const int c0 = cg * 64 + ch * 16;
            float f[16];
#pragma unroll
            for (int jj = 0; jj < 16; ++jj) f[jj] = feat[(size_t)(kb * 256 + c0 + jj) * NS + sI];
#pragma unroll
            for (int jj = 0; jj < 16; ++jj) {
                const int c = c0 + jj;
#pragma unroll
                for (int e = 0; e < En; ++e) {
                    kk[e] += w_k[e * 256 + c] * f[jj];
                    vv[e] += w_v[e * 256 + c] * f[jj];
                }
            }
        }
#pragma unroll
        for (int e = 0; e < En; ++e) {
            pkv[((size_t)(g * NS + sI)) * 24 + e] = kk[e];
            pkv[((size_t)(g * NS + sI)) * 24 + 12 + e] = vv[e];
        }
    }
}

// ---------- K2: attention (3 pos/thread) + zb(NT) + Gram-form analytic stats ----------
__global__ __launch_bounds__(256) void k_attn(const unsigned* __restrict__ qp,
                                              const float* __restrict__ pkv,
                                              const float* __restrict__ w_q,
                                              const float* __restrict__ gniw,
                                              const float* __restrict__ gnib,
                                              const float2* __restrict__ part1,
                                              const float* __restrict__ w_out,
                                              unsigned short* __restrict__ zb,
                                              float4* __restrict__ part2) {
    __shared__ float Ks[NS * En], Vs[NS * En], WOs[Cn * En], QBs[En];
    __shared__ float G[En * En], woSum[En];
    __shared__ float kred[2], kscs_sh;
    const int x = blockIdx.x, b = blockIdx.y, tid = threadIdx.x;
    const int u = tid >> 6, lane = tid & 63;

    // exact GN-in stats from part1
    float sP = 0.f, ssP = 0.f;
    for (int i = tid; i < NB1; i += 256) {
        float2 v = part1[b * NB1 + i];
        sP += v.x; ssP += v.y;
    }
    float2 tP = block_red2(sP, ssP);
    const float mGN = tP.x / (float)PERB;
    const float rsGN = rsqrtf(tP.y / (float)PERB - mGN * mGN + EPS);
    const float qsc = rsGN * SQK;

    // combine K/V partials, weights, q-bias
    for (int i = tid; i < NS * En; i += 256) {
        int s = i / En, e = i - s * En;
        size_t base = ((size_t)((b * 4) * NS + s)) * 24 + e;
        Ks[i] = pkv[base] + pkv[base + 3072] + pkv[base + 6144] + pkv[base + 9216];
        Vs[i] = pkv[base + 12] + pkv[base + 3084] + pkv[base + 6156] + pkv[base + 9228];
    }
    for (int i = tid; i < Cn * En; i += 256) WOs[i] = w_out[i];
    if (tid < En) {
        float acc = 0.f;
        for (int c = 0; c < Cn; ++c)
            acc += w_q[tid * Cn + c] * (gnib[c] - mGN * rsGN * gniw[c]);
        QBs[tid] = SQK * acc;
    }
    __syncthreads();
    // Gram matrix, column sums, kscs
    if (tid < 144) {
        int e1 = tid / 12, e2 = tid - e1 * 12;
        float a = 0.f;
        for (int c = 0; c < Cn; ++c) a += WOs[c * En + e1] * WOs[c * En + e2];
        G[tid] = a;
    }
    if (tid >= 144 && tid < 156) {
        int e = tid - 144;
        float a = 0.f;
        for (int c = 0; c < Cn; ++c) a += WOs[c * En + e];
        woSum[e] = a;
    }
    if (tid < NS) {
        float n2 = 0.f;
#pragma unroll
        for (int e = 0; e < En; ++e) { float k = Ks[tid * En + e]; n2 += k * k; }
#pragma unroll
        for (int off = 32; off; off >>= 1) n2 = fmaxf(n2, __shfl_down(n2, off, 64));
        if (!(tid & 63)) kred[tid >> 6] = n2;
    }
    __syncthreads();
    if (!tid) kscs_sh = sqrtf(fmaxf(kred[0], kred[1]));
    __syncthreads();
    const float kscs = kscs_sh;

    // positions: n_p = x*768 + (u*3+p)*64 + lane  (3 consecutive h-rows; w == lane)
    int npos[3];
#pragma unroll
    for (int p = 0; p < 3; ++p) npos[p] = x * 768 + (u * 3 + p) * 64 + lane;

    float pwv[3][En];  // hi half saved for spz
    f4v q[3][3];
    float ub[3];
#pragma unroll
    for (int p = 0; p < 3; ++p) {
        const int n = npos[p];
        float qn2 = 0.f;
#pragma unroll
        for (int v = 0; v < 3; ++v) {
            f4v t;
#pragma unroll
            for (int uu = 0; uu < 4; ++uu) {
                int e = v * 4 + uu;
                unsigned pk = qp[(size_t)(b * En + e) * NPB + n];
                float qe = qsc * b2f((unsigned short)(pk & 0xffffu)) + QBs[e];
                pwv[p][e] = b2f((unsigned short)(pk >> 16));
                t[uu] = qe;
                qn2 += qe * qe;
            }
            q[p][v] = t;
        }
        ub[p] = sqrtf(qn2) * kscs;  // Cauchy-Schwarz >= max logit
    }

    f4v o0[3], o1[3], o2[3];
    float l[3];
#pragma unroll
    for (int p = 0; p < 3; ++p) {
        o0[p] = (f4v)(0.f); o1[p] = (f4v)(0.f); o2[p] = (f4v)(0.f);
        l[p] = 0.f;
    }
    const f4v* K4 = (const f4v*)Ks;
    const f4v* V4 = (const f4v*)Vs;
    for (int s = 0; s < NS; ++s) {
        f4v k0 = K4[s * 3], k1 = K4[s * 3 + 1], k2 = K4[s * 3 + 2];
        f4v v0 = V4[s * 3], v1 = V4[s * 3 + 1], v2 = V4[s * 3 + 2];
#pragma unroll
        for (int p = 0; p < 3; ++p) {
            f4v d4 = q[p][0] * k0 + q[p][1] * k1 + q[p][2] * k2;
            float dot = (d4.x + d4.y) + (d4.z + d4.w);
            float pe = __expf(dot - ub[p]);
            l[p] += pe;
            o0[p] += pe * v0; o1[p] += pe * v1; o2[p] += pe * v2;
        }
    }

    // h = o / l
    float hv[3][En];
#pragma unroll
    for (int p = 0; p < 3; ++p) {
        float iv = 1.0f / l[p];
#pragma unroll
        for (int uu = 0; uu < 4; ++uu) {
            hv[p][uu] = o0[p][uu] * iv;
            hv[p][4 + uu] = o1[p][uu] * iv;
            hv[p][8 + uu] = o2[p][uu] * iv;
        }
    }

    // per-channel Z -> zb (bf16, NT — read once much later; keep out of L3)
    for (int c = 0; c < Cn; ++c) {
        float z[3];
#pragma unroll
        for (int p = 0; p < 3; ++p) {
            float a = 0.f;
#pragma unroll
            for (int e = 0; e < En; ++e) a += WOs[c * En + e] * hv[p][e];
            z[p] = a;
        }
#pragma unroll
        for (int p = 0; p < 3; ++p)
            __builtin_nontemporal_store(bf16b(z[p]),
                                        zb + (size_t)(b * Cn + c) * NPB + npos[p]);
    }

    // sz, spz  (pw kept in registers)
    float sz = 0.f, spz = 0.f;
#pragma unroll
    for (int p = 0; p < 3; ++p) {
#pragma unroll
        for (int e = 0; e < En; ++e) {
            sz += woSum[e] * hv[p][e];
            spz += pwv[p][e] * hv[p][e];
        }
    }

    // shuffled neighbors (w+1): zero at lane 63 (slice edge)
    const bool okw = (lane < 63);
    float hs[3][En];
#pragma unroll
    for (int p = 0; p < 3; ++p)
#pragma unroll
        for (int e = 0; e < En; ++e) {
            float t = __shfl_down(hv[p][e], 1, 64);
            hs[p][e] = okw ? t : 0.f;
        }

    // geometry weights
    float hD[3];
    bool hOk[3];
#pragma unroll
    for (int p = 0; p < 3; ++p) {
        int h = (x * 12 + u * 3 + p) & 31;
        hD[p] = (h == 0 || h == 31) ? 1.625f : 1.25f;
        hOk[p] = (h < 31) && (p < 2);
    }
    const float Dw = (lane == 0 || lane == 63) ? 1.625f : 1.25f;

    // t2 via Gram
    float t2 = 0.f;
#pragma unroll
    for (int p = 0; p < 3; ++p) {
        float Gh[En];
#pragma unroll
        for (int e = 0; e < En; ++e) {
            float a = 0.f;
#pragma unroll
            for (int f = 0; f < En; ++f) a += G[e * En + f] * hv[p][f];
            Gh[e] = a;
        }
        float gpp = 0.f, gw = 0.f;
#pragma unroll
        for (int e = 0; e < En; ++e) {
            gpp += Gh[e] * hv[p][e];
            gw += Gh[e] * hs[p][e];
        }
        t2 += hD[p] * Dw * gpp + 0.75f * hD[p] * gw;
        if (p < 2 && hOk[p]) {
            float ghp = 0.f, gd1 = 0.f;
#pragma unroll
            for (int e = 0; e < En; ++e) {
                ghp += Gh[e] * hv[p + 1][e];
                gd1 += Gh[e] * hs[p + 1][e];
            }
            t2 += 0.75f * Dw * ghp + 0.28125f * gd1;
        }
        if (p > 0 && hOk[p - 1]) {
            float gd2 = 0.f;
#pragma unroll
            for (int e = 0; e < En; ++e) gd2 += Gh[e] * hs[p - 1][e];
            t2 += 0.28125f * gd2;
        }
    }
    float2 rA = block_red2(sz, spz);
    float2 rB = block_red2(t2, 0.f);
    if (!tid) part2[b * NBA + x] = make_float4(rA.x, rA.y, rB.x, 0.f);
}

// ---------- K2b: finalize stats2 (4 blocks) ----------
__global__ __launch_bounds__(256) void k_st2(const float2* __restrict__ part1,
                                             const float4* __restrict__ part2,
                                             const float* __restrict__ gamma_p,
                                             float2* __restrict__ st2) {
    const int b = blockIdx.x, tid = threadIdx.x;
    const float g = gamma_p[0];
    float sc_ = 0.f, scc = 0.f;
    for (int i = tid; i < NB1; i += 256) {
        float2 v = part1[b * NB1 + i];
        sc_ += v.x; scc += v.y;
    }
    float2 tA = block_red2(sc_, scc);
    float sz = 0.f, spz = 0.f, t2 = 0.f;
    if (tid < NBA) {
        float4 v = part2[b * NBA + tid];
        sz = v.x; spz = v.y; t2 = v.z;
    }
    float2 tB = block_red2(sz, spz);
    float2 tC = block_red2(t2, 0.f);
    if (!tid) {
        const float Sy = tA.x + 4.f * g * tB.x;
        const float Syy = tA.y + 8.f * g * tB.y + g * g * tC.x;
        const float m = Sy / (float)PERB;
        const float var = Syy / (float)PERB - m * m;
        st2[b] = make_float2(m, rsqrtf(var + EPS));
    }
}

// ---------- K3: final GroupNorm (single stats load), hoisted upsample ----------
__global__ __launch_bounds__(256) void k_final(const float* __restrict__ cost,
                                               const unsigned short* __restrict__ zb,
                                               const float* __restrict__ gamma_p,
                                               const float2* __restrict__ st2,
                                               const float* __restrict__ gow,
                                               const float* __restrict__ gob,
                                               float* __restrict__ out) {
    const int blk = blockIdx.x;
    const int b = blk / (Cn * Dn);
    const int c = (blk / Dn) % Cn;
    const int tid = threadIdx.x;
    const float g = gamma_p[0];
    const float2 st = st2[b];
    const float m = st.x, rs = st.y;

    // stage z-slice as FLOATS (8 KB), NT loads
    __shared__ float zs[HQ * WQ];
    {
        const unsigned int* zsrc = (const unsigned int*)(zb + (size_t)blk * 2048);
        for (int i = tid; i < 1024; i += 256) {
            unsigned v = __builtin_nontemporal_load(zsrc + i);
            zs[2 * i] = b2f((unsigned short)(v & 0xffffu));
            zs[2 * i + 1] = b2f((unsigned short)(v >> 16));
        }
    }
    __syncthreads();
    const float sc = rs * gow[c], bi = gob[c];
    const f4v* cq = (const f4v*)(cost + (size_t)blk * 8192);
    f4v* oq = (f4v*)(out + (size_t)blk * 8192);

    // thread-invariant upsample geometry
    const int hbase = tid >> 5;           // 0..7
    const int w4 = (tid & 31) << 2;       // 0..124
    const float wh0 = (hbase & 1) ? 0.75f : 0.25f;
    const float wh1 = 1.0f - wh0;
    const int ia = (w4 >> 1) - 1 < 0 ? 0 : (w4 >> 1) - 1;
    const int ib = w4 >> 1;
    const int ic = (w4 >> 1) + 1;
    const int id = (w4 >> 1) + 2 > WQ - 1 ? WQ - 1 : (w4 >> 1) + 2;

#pragma unroll
    for (int k = 0; k < 8; ++k) {
        const int h = hbase + 8 * k;
        int h0 = (h - 1) >> 1;
        h0 = h0 < 0 ? 0 : h0;
        int h1 = h0 + 1;
        h1 = h1 > HQ - 1 ? HQ - 1 : h1;
        const float* r0 = zs + h0 * WQ;
        const float* r1 = zs + h1 * WQ;
        const float a0 = r0[ia], b0 = r0[ib], c0 = r0[ic], d0 = r0[id];
        const float a1 = r1[ia], b1 = r1[ib], c1 = r1[ic], d1 = r1[id];
        const float t0j = 0.25f * a0 + 0.75f * b0, u0j = 0.25f * a1 + 0.75f * b1;
        const float t1j = 0.75f * b0 + 0.25f * c0, u1j = 0.75f * b1 + 0.25f * c1;
        const float t2j = 0.25f * b0 + 0.75f * c0, u2j = 0.25f * b1 + 0.75f * c1;
        const float t3j = 0.75f * c0 + 0.25f * d0, u3j = 0.75f * c1 + 0.25f * d1;
        const int qd = tid + 256 * k;
        f4v cv = cq[qd];
        f4v ov;
        ov.x = (cv.x + g * bf16_rne(wh0 * t0j + wh1 * u0j) - m) * sc + bi;
        ov.y = (cv.y + g * bf16_rne(wh0 * t1j + wh1 * u1j) - m) * sc + bi;
        ov.z = (cv.z + g * bf16_rne(wh0 * t2j + wh1 * u2j) - m) * sc + bi;
        ov.w = (cv.w + g * bf16_rne(wh0 * t3j + wh1 * u3j) - m) * sc + bi;
        __builtin_nontemporal_store(ov, oq + qd);
    }
}

extern "C" void kernel_launch(void* const* d_in, const int* in_sizes, int n_in,
                              void* d_out, int out_size, void* d_ws, size_t ws_size,
                              hipStream_t stream) {
    const float* cost  = (const float*)d_in[0];
    const float* feat  = (const float*)d_in[1];
    const float* w_q   = (const float*)d_in[2];
    const float* w_k   = (const float*)d_in[3];
    const float* w_v   = (const float*)d_in[4];
    const float* w_out = (const float*)d_in[5];
    const float* gniw  = (const float*)d_in[6];
    const float* gnib  = (const float*)d_in[7];
    const float* gow   = (const float*)d_in[8];
    const float* gob   = (const float*)d_in[9];
    const float* gamma = (const float*)d_in[10];

    float* ws = (float*)d_ws;
    float* outp = (float*)d_out;

    unsigned short* zb = (unsigned short*)(ws + OFF_ZB);
    unsigned* qp = (unsigned*)(ws + OFF_QP);
    float2* part1 = (float2*)(ws + OFF_P1);
    float4* part2 = (float4*)(ws + OFF_P2);
    float2* st2 = (float2*)(ws + OFF_ST2);
    float* pkv = ws + OFF_PKV;

    k1_pool<<<dim3(NB1, Bn), 256, 0, stream>>>(cost, feat, w_q, w_k, w_v, w_out, gniw,
                                               qp, part1, pkv);
    k_attn<<<dim3(NBA, Bn), 256, 0, stream>>>(qp, pkv, w_q, gniw, gnib, part1,
                                              w_out, zb, part2);
    k_st2<<<Bn, 256, 0, stream>>>(part1, part2, gamma, st2);
    k_final<<<Bn * Cn * Dn, 256, 0, stream>>>(cost, zb, gamma, st2, gow, gob, outp);
}